// Round 1
// baseline (521.561 us; speedup 1.0000x reference)
//
#include <hip/hip_runtime.h>

// Problem constants (from setup_inputs): bs=16384, C=10000, M=6, D=256
constexpr int kBS = 16384;
constexpr int kC  = 10000;
constexpr int kM  = 6;
constexpr int kD  = 256;
constexpr float kEPS = 1e-4f;

// One wave (64 lanes) per batch row; 4 rows per 256-thread block.
// Per row: tiny MLP -> norm_w[6]; then lane i owns float4 chunk d=4i..4i+3:
//   - weighted center reduce for the loss term
//   - scatter-add data*norm_w into mem_out (atomic f32, low contention)
__global__ __launch_bounds__(256) void mc_main(
    const float* __restrict__ data,     // [BS, D]
    const int*   __restrict__ labels,   // [BS]
    const float* __restrict__ beta,     // [BS]
    const float* __restrict__ centers,  // [C*M, D]
    const float* __restrict__ W1,       // [M, C]
    const float* __restrict__ b1,       // [M]
    const float* __restrict__ W2,       // [M, M]
    const float* __restrict__ b2,       // [M]
    float*       loss_out,              // scalar accumulator (pre-zeroed)
    float* __restrict__ sum_v,          // [BS, M]
    float*       mem_out,               // [C*M, D] (pre-initialized = memory)
    float*       mw_out)                // [C*M]    (pre-initialized = memory_weights)
{
    __shared__ float ls[4];
    const int tid  = blockIdx.x * 256 + threadIdx.x;
    const int row  = tid >> 6;
    const int lane = tid & 63;
    const int wid  = threadIdx.x >> 6;

    const int   lab = labels[row];
    const float bet = beta[row];

    // ---- tiny MLP, computed redundantly in every lane (broadcast loads) ----
    float h[kM];
#pragma unroll
    for (int m = 0; m < kM; ++m) {
        float v = W1[m * kC + lab] + b1[m];   // W1.T[lab][m]
        h[m] = v > 0.f ? v : 0.f;
    }

    float nw[kM];      // un-normalized then normalized weights
    float csarr[kM];   // cumsum(out)
    float cs = 0.f, wsum = 0.f;
#pragma unroll
    for (int m = 0; m < kM; ++m) {
        float z = b2[m];
#pragma unroll
        for (int j = 0; j < kM; ++j) z += W2[m * kM + j] * h[j];
        float o = 1.f / (1.f + expf(-z)) + kEPS;   // sigmoid + EPS
        cs += o;
        csarr[m] = cs;
        float dvb = bet - cs;
        float wv = expf(-sqrtf(dvb * dvb + 1e-10f));
        nw[m] = wv;
        wsum += wv;
    }
    const float inv = 1.f / (wsum + kEPS + 1e-10f);
#pragma unroll
    for (int m = 0; m < kM; ++m) nw[m] *= inv;

    if (lane == 0) {
#pragma unroll
        for (int m = 0; m < kM; ++m) sum_v[row * kM + m] = csarr[m];
    }

    // ---- vector part: lane owns 4 contiguous d's ----
    const size_t cbase = (size_t)lab * (kM * kD);
    const float4 dv = ((const float4*)(data + (size_t)row * kD))[lane];

    float4 cm = make_float4(0.f, 0.f, 0.f, 0.f);
#pragma unroll
    for (int m = 0; m < kM; ++m) {
        const float4 cv = ((const float4*)(centers + cbase + (size_t)m * kD))[lane];
        cm.x += nw[m] * cv.x;
        cm.y += nw[m] * cv.y;
        cm.z += nw[m] * cv.z;
        cm.w += nw[m] * cv.w;
    }
    const float ax = dv.x - cm.x, ay = dv.y - cm.y;
    const float az = dv.z - cm.z, aw = dv.w - cm.w;
    float acc = ax * ax + ay * ay + az * az + aw * aw;

    // scatter-add weighted features (avg ~1.6 rows/label -> low contention)
#pragma unroll
    for (int m = 0; m < kM; ++m) {
        float* p = mem_out + cbase + (size_t)m * kD + lane * 4;
        atomicAdd(p + 0, dv.x * nw[m]);
        atomicAdd(p + 1, dv.y * nw[m]);
        atomicAdd(p + 2, dv.z * nw[m]);
        atomicAdd(p + 3, dv.w * nw[m]);
    }
    if (lane == 0) {
#pragma unroll
        for (int m = 0; m < kM; ++m) atomicAdd(mw_out + (size_t)lab * kM + m, nw[m]);
    }

    // ---- loss reduction: wave shuffle -> LDS -> one atomic per block ----
#pragma unroll
    for (int off = 32; off > 0; off >>= 1) acc += __shfl_down(acc, off, 64);
    if (lane == 0) ls[wid] = acc;
    __syncthreads();
    if (threadIdx.x == 0) {
        const float s = ls[0] + ls[1] + ls[2] + ls[3];
        atomicAdd(loss_out, s * (1.f / ((float)kBS * (float)kD)));
    }
}

extern "C" void kernel_launch(void* const* d_in, const int* in_sizes, int n_in,
                              void* d_out, int out_size, void* d_ws, size_t ws_size,
                              hipStream_t stream) {
    const float* data    = (const float*)d_in[0];
    const int*   labels  = (const int*)  d_in[1];
    const float* beta    = (const float*)d_in[2];
    const float* centers = (const float*)d_in[3];
    const float* W1      = (const float*)d_in[4];
    const float* b1      = (const float*)d_in[5];
    const float* W2      = (const float*)d_in[6];
    const float* b2      = (const float*)d_in[7];
    const float* memory  = (const float*)d_in[8];
    const float* memw    = (const float*)d_in[9];

    float* out     = (float*)d_out;
    float* loss    = out;                                   // [1]
    float* sum_v   = out + 1;                               // [BS*M]
    float* mem_out = out + 1 + (size_t)kBS * kM;            // [C*M*D]
    float* mw_out  = mem_out + (size_t)kC * kM * kD;        // [C*M]

    // Initialize outputs that are accumulated into (d_out is poisoned 0xAA).
    hipMemsetAsync(loss, 0, sizeof(float), stream);
    hipMemcpyAsync(mem_out, memory, (size_t)kC * kM * kD * sizeof(float),
                   hipMemcpyDeviceToDevice, stream);
    hipMemcpyAsync(mw_out, memw, (size_t)kC * kM * sizeof(float),
                   hipMemcpyDeviceToDevice, stream);

    mc_main<<<dim3(kBS / 4), dim3(256), 0, stream>>>(
        data, labels, beta, centers, W1, b1, W2, b2,
        loss, sum_v, mem_out, mw_out);
}

// Round 2
// 261.592 us; speedup vs baseline: 1.9938x; 1.9938x over previous
//
#include <hip/hip_runtime.h>

// Problem constants: bs=16384, C=10000, M=6, D=256
constexpr int kBS = 16384;
constexpr int kC  = 10000;
constexpr int kM  = 6;
constexpr int kD  = 256;
constexpr float kEPS = 1e-4f;

// ---------------- Kernel 1: per-row MLP + loss + sum_v + histogram ----------
// One wave (64 lanes) per row, 4 rows per block.
__global__ __launch_bounds__(256) void k_row(
    const float* __restrict__ data,     // [BS, D]
    const int*   __restrict__ labels,   // [BS]
    const float* __restrict__ beta,     // [BS]
    const float* __restrict__ centers,  // [C*M, D]
    const float* __restrict__ W1,       // [M, C]
    const float* __restrict__ b1,       // [M]
    const float* __restrict__ W2,       // [M, M]
    const float* __restrict__ b2,       // [M]
    float*       loss_out,              // scalar (pre-zeroed)
    float* __restrict__ sum_v,          // [BS, M]
    float* __restrict__ nw_out,         // ws: [BS, M] normalized weights
    int*         counts)                // ws: [C] histogram (pre-zeroed)
{
    __shared__ float ls[4];
    const int tid  = blockIdx.x * 256 + threadIdx.x;
    const int row  = tid >> 6;
    const int lane = tid & 63;
    const int wid  = threadIdx.x >> 6;

    const int   lab = labels[row];
    const float bet = beta[row];

    // tiny MLP, redundant in every lane (broadcast loads)
    float h[kM];
#pragma unroll
    for (int m = 0; m < kM; ++m) {
        float v = W1[m * kC + lab] + b1[m];
        h[m] = v > 0.f ? v : 0.f;
    }
    float nw[kM], csarr[kM];
    float cs = 0.f, wsum = 0.f;
#pragma unroll
    for (int m = 0; m < kM; ++m) {
        float z = b2[m];
#pragma unroll
        for (int j = 0; j < kM; ++j) z += W2[m * kM + j] * h[j];
        float o = 1.f / (1.f + expf(-z)) + kEPS;
        cs += o;
        csarr[m] = cs;
        float dvb = bet - cs;
        float wv = expf(-sqrtf(dvb * dvb + 1e-10f));
        nw[m] = wv;
        wsum += wv;
    }
    const float inv = 1.f / (wsum + kEPS + 1e-10f);
#pragma unroll
    for (int m = 0; m < kM; ++m) nw[m] *= inv;

    if (lane < kM) {
        sum_v[row * kM + lane]  = csarr[lane];
        nw_out[row * kM + lane] = nw[lane];
    }
    if (lane == 0) atomicAdd(counts + lab, 1);

    // loss: lane owns float4 chunk of D
    const size_t cbase = (size_t)lab * (kM * kD);
    const float4 dv = ((const float4*)(data + (size_t)row * kD))[lane];
    float4 cm = make_float4(0.f, 0.f, 0.f, 0.f);
#pragma unroll
    for (int m = 0; m < kM; ++m) {
        const float4 cv = ((const float4*)(centers + cbase + (size_t)m * kD))[lane];
        cm.x += nw[m] * cv.x; cm.y += nw[m] * cv.y;
        cm.z += nw[m] * cv.z; cm.w += nw[m] * cv.w;
    }
    const float ax = dv.x - cm.x, ay = dv.y - cm.y;
    const float az = dv.z - cm.z, aw = dv.w - cm.w;
    float acc = ax * ax + ay * ay + az * az + aw * aw;

#pragma unroll
    for (int off = 32; off > 0; off >>= 1) acc += __shfl_down(acc, off, 64);
    if (lane == 0) ls[wid] = acc;
    __syncthreads();
    if (threadIdx.x == 0) {
        const float s = ls[0] + ls[1] + ls[2] + ls[3];
        atomicAdd(loss_out, s * (1.f / ((float)kBS * (float)kD)));
    }
}

// ---------------- Kernel 2: exclusive scan of counts -> starts, cursor ------
__global__ __launch_bounds__(256) void k_scan(
    const int* __restrict__ counts, int* __restrict__ starts, int* __restrict__ cursor)
{
    __shared__ int part[256];
    const int t = threadIdx.x;
    const int base = t * 40;                 // 256*40 = 10240 >= 10000
    int local[40];
    int s = 0;
#pragma unroll
    for (int i = 0; i < 40; ++i) {
        int idx = base + i;
        int c = (idx < kC) ? counts[idx] : 0;
        local[i] = s;
        s += c;
    }
    part[t] = s;
    __syncthreads();
    // Hillis-Steele inclusive scan over 256 partials
    for (int off = 1; off < 256; off <<= 1) {
        int v = part[t];
        int add = (t >= off) ? part[t - off] : 0;
        __syncthreads();
        part[t] = v + add;
        __syncthreads();
    }
    const int excl = part[t] - s;
#pragma unroll
    for (int i = 0; i < 40; ++i) {
        int idx = base + i;
        if (idx < kC) {
            int v = excl + local[i];
            starts[idx] = v;
            cursor[idx] = v;
        }
    }
    if (t == 255) starts[kC] = excl + s;     // == kBS
}

// ---------------- Kernel 3: scatter row ids into label-sorted order ---------
__global__ __launch_bounds__(256) void k_scatter(
    const int* __restrict__ labels, int* __restrict__ cursor, int* __restrict__ order)
{
    const int row = blockIdx.x * 256 + threadIdx.x;
    if (row < kBS) {
        const int lab = labels[row];
        const int pos = atomicAdd(cursor + lab, 1);
        order[pos] = row;
    }
}

// ---------------- Kernel 4: label-major aggregation (no atomics) ------------
// One wave per label, 4 labels per block. Lane owns float4 chunk of D.
__global__ __launch_bounds__(256) void k_agg(
    const float* __restrict__ data,     // [BS, D]
    const float* __restrict__ nw_in,    // ws: [BS, M]
    const int*   __restrict__ starts,   // ws: [C+1]
    const int*   __restrict__ order,    // ws: [BS]
    const float* __restrict__ memory,   // [C*M, D]
    const float* __restrict__ memw,     // [C*M]
    float* __restrict__ mem_out,        // [C*M, D]
    float* __restrict__ mw_out)         // [C*M]
{
    const int wid  = threadIdx.x >> 6;
    const int lane = threadIdx.x & 63;
    const int lab  = blockIdx.x * 4 + wid;
    if (lab >= kC) return;

    const int s0 = starts[lab];
    const int s1 = starts[lab + 1];

    float4 acc[kM];
#pragma unroll
    for (int m = 0; m < kM; ++m) acc[m] = make_float4(0.f, 0.f, 0.f, 0.f);
    float mwacc[kM];
#pragma unroll
    for (int m = 0; m < kM; ++m) mwacc[m] = 0.f;

    for (int p = s0; p < s1; ++p) {
        const int row = order[p];
        const float4 dv = ((const float4*)(data + (size_t)row * kD))[lane];
        float nw[kM];
#pragma unroll
        for (int m = 0; m < kM; ++m) nw[m] = nw_in[row * kM + m];  // broadcast
#pragma unroll
        for (int m = 0; m < kM; ++m) {
            acc[m].x += dv.x * nw[m]; acc[m].y += dv.y * nw[m];
            acc[m].z += dv.z * nw[m]; acc[m].w += dv.w * nw[m];
            mwacc[m] += nw[m];
        }
    }

    const size_t cbase = (size_t)lab * (kM * kD);
#pragma unroll
    for (int m = 0; m < kM; ++m) {
        const float4 mv = ((const float4*)(memory + cbase + (size_t)m * kD))[lane];
        float4 o;
        o.x = mv.x + acc[m].x; o.y = mv.y + acc[m].y;
        o.z = mv.z + acc[m].z; o.w = mv.w + acc[m].w;
        ((float4*)(mem_out + cbase + (size_t)m * kD))[lane] = o;
    }
    if (lane < kM) {
        const size_t i = (size_t)lab * kM + lane;
        mw_out[i] = memw[i] + (lane < kM ? mwacc[lane] : 0.f);
    }
}

extern "C" void kernel_launch(void* const* d_in, const int* in_sizes, int n_in,
                              void* d_out, int out_size, void* d_ws, size_t ws_size,
                              hipStream_t stream) {
    const float* data    = (const float*)d_in[0];
    const int*   labels  = (const int*)  d_in[1];
    const float* beta    = (const float*)d_in[2];
    const float* centers = (const float*)d_in[3];
    const float* W1      = (const float*)d_in[4];
    const float* b1      = (const float*)d_in[5];
    const float* W2      = (const float*)d_in[6];
    const float* b2      = (const float*)d_in[7];
    const float* memory  = (const float*)d_in[8];
    const float* memw    = (const float*)d_in[9];

    float* out     = (float*)d_out;
    float* loss    = out;                                   // [1]
    float* sum_v   = out + 1;                               // [BS*M]
    float* mem_out = out + 1 + (size_t)kBS * kM;            // [C*M*D]
    float* mw_out  = mem_out + (size_t)kC * kM * kD;        // [C*M]

    // workspace layout (all 4-byte types)
    int*   counts = (int*)d_ws;                             // [C]
    int*   starts = counts + kC;                            // [C+1]
    int*   cursor = starts + kC + 1;                        // [C]
    int*   order  = cursor + kC;                            // [BS]
    float* nw_ws  = (float*)(order + kBS);                  // [BS*M]

    hipMemsetAsync(loss, 0, sizeof(float), stream);
    hipMemsetAsync(counts, 0, kC * sizeof(int), stream);

    k_row<<<dim3(kBS / 4), dim3(256), 0, stream>>>(
        data, labels, beta, centers, W1, b1, W2, b2,
        loss, sum_v, nw_ws, counts);

    k_scan<<<dim3(1), dim3(256), 0, stream>>>(counts, starts, cursor);

    k_scatter<<<dim3((kBS + 255) / 256), dim3(256), 0, stream>>>(labels, cursor, order);

    k_agg<<<dim3((kC + 3) / 4), dim3(256), 0, stream>>>(
        data, nw_ws, starts, order, memory, memw, mem_out, mw_out);
}

// Round 3
// 207.383 us; speedup vs baseline: 2.5150x; 1.2614x over previous
//
#include <hip/hip_runtime.h>

// Problem constants: bs=16384, C=10000, M=6, D=256
constexpr int kBS = 16384;
constexpr int kC  = 10000;
constexpr int kM  = 6;
constexpr int kD  = 256;
constexpr float kEPS = 1e-4f;

// ---------- Kernel 1: per-row tiny MLP -> sum_v, nw; linked-list push -------
// One THREAD per row. 256 blocks x 64 threads (spread across all CUs).
__global__ __launch_bounds__(64) void k_row(
    const int*   __restrict__ labels,   // [BS]
    const float* __restrict__ beta,     // [BS]
    const float* __restrict__ W1,       // [M, C]
    const float* __restrict__ b1,       // [M]
    const float* __restrict__ W2,       // [M, M]
    const float* __restrict__ b2,       // [M]
    float* __restrict__ sum_v,          // [BS, M] (output)
    float* __restrict__ nw_out,         // ws: [BS, M]
    int*         head,                  // ws: [C], pre-set to -1
    int*   __restrict__ next)           // ws: [BS]
{
    const int row = blockIdx.x * 64 + threadIdx.x;
    const int lab = labels[row];
    const float bet = beta[row];

    float h[kM];
#pragma unroll
    for (int m = 0; m < kM; ++m) {
        float v = W1[m * kC + lab] + b1[m];
        h[m] = v > 0.f ? v : 0.f;
    }
    float nw[kM], csarr[kM];
    float cs = 0.f, wsum = 0.f;
#pragma unroll
    for (int m = 0; m < kM; ++m) {
        float z = b2[m];
#pragma unroll
        for (int j = 0; j < kM; ++j) z += W2[m * kM + j] * h[j];
        float o = 1.f / (1.f + expf(-z)) + kEPS;
        cs += o;
        csarr[m] = cs;
        float dvb = bet - cs;
        float wv = expf(-sqrtf(dvb * dvb + 1e-10f));
        nw[m] = wv;
        wsum += wv;
    }
    const float inv = 1.f / (wsum + kEPS + 1e-10f);
#pragma unroll
    for (int m = 0; m < kM; ++m) {
        sum_v[row * kM + m]  = csarr[m];
        nw_out[row * kM + m] = nw[m] * inv;
    }
    // push row onto label's list (next[] is only read in k_agg, after sync)
    const int old = atomicExch(head + lab, row);
    next[row] = old;
}

// ---------- Kernel 2: label-major aggregation + loss (no scatter atomics) ---
// One wave per label, 4 labels per block. Lane owns float4 chunk of D.
__global__ __launch_bounds__(256) void k_agg(
    const float* __restrict__ data,     // [BS, D]
    const float* __restrict__ nw_in,    // ws: [BS, M]
    const int*   __restrict__ head,     // ws: [C]
    const int*   __restrict__ next,     // ws: [BS]
    const float* __restrict__ centers,  // [C*M, D]
    const float* __restrict__ memory,   // [C*M, D]
    const float* __restrict__ memw,     // [C*M]
    float*       loss_out,              // scalar (pre-zeroed)
    float* __restrict__ mem_out,        // [C*M, D]
    float* __restrict__ mw_out)         // [C*M]
{
    __shared__ float ls[4];
    const int wid  = threadIdx.x >> 6;
    const int lane = threadIdx.x & 63;
    const int lab  = blockIdx.x * 4 + wid;   // grid = 2500 -> labs 0..9999 exactly

    float lossacc = 0.f;

    const size_t cbase = (size_t)lab * (kM * kD);
    int row = head[lab];                      // wave-uniform broadcast load

    float4 acc[kM];
    float  mwacc[kM];
#pragma unroll
    for (int m = 0; m < kM; ++m) {
        acc[m] = make_float4(0.f, 0.f, 0.f, 0.f);
        mwacc[m] = 0.f;
    }

    if (row >= 0) {
        float4 cv[kM];
#pragma unroll
        for (int m = 0; m < kM; ++m)
            cv[m] = ((const float4*)(centers + cbase + (size_t)m * kD))[lane];

        while (row >= 0) {
            const float4 dv = ((const float4*)(data + (size_t)row * kD))[lane];
            float nwv[kM];
#pragma unroll
            for (int m = 0; m < kM; ++m) nwv[m] = nw_in[row * kM + m]; // broadcast
            const int nrow = next[row];       // issue chase early

            float4 cm = make_float4(0.f, 0.f, 0.f, 0.f);
#pragma unroll
            for (int m = 0; m < kM; ++m) {
                cm.x += nwv[m] * cv[m].x; cm.y += nwv[m] * cv[m].y;
                cm.z += nwv[m] * cv[m].z; cm.w += nwv[m] * cv[m].w;
                acc[m].x += nwv[m] * dv.x; acc[m].y += nwv[m] * dv.y;
                acc[m].z += nwv[m] * dv.z; acc[m].w += nwv[m] * dv.w;
                mwacc[m] += nwv[m];
            }
            const float ax = dv.x - cm.x, ay = dv.y - cm.y;
            const float az = dv.z - cm.z, aw = dv.w - cm.w;
            lossacc += ax * ax + ay * ay + az * az + aw * aw;
            row = nrow;
        }
    }

    // write mem_out = memory + acc (every label, every chunk: full coverage)
#pragma unroll
    for (int m = 0; m < kM; ++m) {
        const float4 mv = ((const float4*)(memory + cbase + (size_t)m * kD))[lane];
        float4 o;
        o.x = mv.x + acc[m].x; o.y = mv.y + acc[m].y;
        o.z = mv.z + acc[m].z; o.w = mv.w + acc[m].w;
        ((float4*)(mem_out + cbase + (size_t)m * kD))[lane] = o;
    }
    // mw_out (lane m writes element m; mwacc is lane-uniform)
    float msel = mwacc[0];
    msel = (lane == 1) ? mwacc[1] : msel;
    msel = (lane == 2) ? mwacc[2] : msel;
    msel = (lane == 3) ? mwacc[3] : msel;
    msel = (lane == 4) ? mwacc[4] : msel;
    msel = (lane == 5) ? mwacc[5] : msel;
    if (lane < kM) {
        const size_t i = (size_t)lab * kM + lane;
        mw_out[i] = memw[i] + msel;
    }

    // loss: wave shuffle -> LDS -> one atomic per block
#pragma unroll
    for (int off = 32; off > 0; off >>= 1) lossacc += __shfl_down(lossacc, off, 64);
    if (lane == 0) ls[wid] = lossacc;
    __syncthreads();
    if (threadIdx.x == 0) {
        const float s = ls[0] + ls[1] + ls[2] + ls[3];
        atomicAdd(loss_out, s * (1.f / ((float)kBS * (float)kD)));
    }
}

extern "C" void kernel_launch(void* const* d_in, const int* in_sizes, int n_in,
                              void* d_out, int out_size, void* d_ws, size_t ws_size,
                              hipStream_t stream) {
    const float* data    = (const float*)d_in[0];
    const int*   labels  = (const int*)  d_in[1];
    const float* beta    = (const float*)d_in[2];
    const float* centers = (const float*)d_in[3];
    const float* W1      = (const float*)d_in[4];
    const float* b1      = (const float*)d_in[5];
    const float* W2      = (const float*)d_in[6];
    const float* b2      = (const float*)d_in[7];
    const float* memory  = (const float*)d_in[8];
    const float* memw    = (const float*)d_in[9];

    float* out     = (float*)d_out;
    float* loss    = out;                                   // [1]
    float* sum_v   = out + 1;                               // [BS*M]
    float* mem_out = out + 1 + (size_t)kBS * kM;            // [C*M*D]
    float* mw_out  = mem_out + (size_t)kC * kM * kD;        // [C*M]

    // workspace layout
    int*   head  = (int*)d_ws;                              // [C]
    int*   next  = head + kC;                               // [BS]
    float* nw_ws = (float*)(next + kBS);                    // [BS*M]

    hipMemsetAsync(loss, 0, sizeof(float), stream);
    hipMemsetAsync(head, 0xFF, kC * sizeof(int), stream);   // head[i] = -1

    k_row<<<dim3(kBS / 64), dim3(64), 0, stream>>>(
        labels, beta, W1, b1, W2, b2, sum_v, nw_ws, head, next);

    k_agg<<<dim3(kC / 4), dim3(256), 0, stream>>>(
        data, nw_ws, head, next, centers, memory, memw,
        loss, mem_out, mw_out);
}

// Round 4
// 203.917 us; speedup vs baseline: 2.5577x; 1.0170x over previous
//
#include <hip/hip_runtime.h>

// Problem constants: bs=16384, C=10000, M=6, D=256
constexpr int kBS = 16384;
constexpr int kC  = 10000;
constexpr int kM  = 6;
constexpr int kD  = 256;
constexpr float kEPS = 1e-4f;

// ---------- Kernel 1: build per-label linked lists (and zero loss) ----------
__global__ __launch_bounds__(256) void k_build(
    const int* __restrict__ labels,   // [BS]
    int*       head,                  // ws: [C], pre-set to -1 (memset 0xFF)
    int* __restrict__ next,           // ws: [BS]
    float*     loss_out)              // d_out slot, must be zeroed
{
    const int row = blockIdx.x * 256 + threadIdx.x;
    if (row == 0) *loss_out = 0.f;
    if (row < kBS) {
        const int lab = labels[row];
        next[row] = atomicExch(head + lab, row);
    }
}

// ---------- Kernel 2: everything else, label-major --------------------------
// One wave per label, 4 labels per block. Lane owns float4 chunk of D.
// MLP head (h, sigmoid, cumsum) depends ONLY on the label -> once per wave.
__global__ __launch_bounds__(256) void k_agg(
    const float* __restrict__ data,     // [BS, D]
    const float* __restrict__ beta,     // [BS]
    const int*   __restrict__ head,     // ws: [C]
    const int*   __restrict__ next,     // ws: [BS]
    const float* __restrict__ W1,       // [M, C]
    const float* __restrict__ b1,       // [M]
    const float* __restrict__ W2,       // [M, M]
    const float* __restrict__ b2,       // [M]
    const float* __restrict__ centers,  // [C*M, D]
    const float* __restrict__ memory,   // [C*M, D]
    const float* __restrict__ memw,     // [C*M]
    float*       loss_out,              // scalar (zeroed by k_build)
    float* __restrict__ sum_v,          // [BS, M]
    float* __restrict__ mem_out,        // [C*M, D]
    float* __restrict__ mw_out)         // [C*M]
{
    __shared__ float ls[4];
    const int wid  = threadIdx.x >> 6;
    const int lane = threadIdx.x & 63;
    const int lab  = blockIdx.x * 4 + wid;   // grid = 2500 -> labels 0..9999

    const size_t cbase = (size_t)lab * (kM * kD);

    // prefetch this label's centers & memory rows (independent of the chase)
    float4 cv[kM], mv[kM];
#pragma unroll
    for (int m = 0; m < kM; ++m) {
        cv[m] = ((const float4*)(centers + cbase + (size_t)m * kD))[lane];
        mv[m] = ((const float4*)(memory  + cbase + (size_t)m * kD))[lane];
    }

    // per-label MLP head: column_sum (csarr) — row-independent!
    float csarr[kM];
    {
        float h[kM];
#pragma unroll
        for (int m = 0; m < kM; ++m) {
            float v = W1[m * kC + lab] + b1[m];
            h[m] = v > 0.f ? v : 0.f;
        }
        float cs = 0.f;
#pragma unroll
        for (int m = 0; m < kM; ++m) {
            float z = b2[m];
#pragma unroll
            for (int j = 0; j < kM; ++j) z += W2[m * kM + j] * h[j];
            cs += 1.f / (1.f + expf(-z)) + kEPS;
            csarr[m] = cs;
        }
    }
    // lane-indexed csarr (for sum_v writes by lanes 0..5)
    float csel = csarr[0];
    csel = (lane == 1) ? csarr[1] : csel;
    csel = (lane == 2) ? csarr[2] : csel;
    csel = (lane == 3) ? csarr[3] : csel;
    csel = (lane == 4) ? csarr[4] : csel;
    csel = (lane == 5) ? csarr[5] : csel;

    float4 acc[kM];
    float  mwacc[kM];
#pragma unroll
    for (int m = 0; m < kM; ++m) {
        acc[m] = make_float4(0.f, 0.f, 0.f, 0.f);
        mwacc[m] = 0.f;
    }
    float lossacc = 0.f;

    int row = head[lab];
    while (row >= 0) {
        // collect up to 4 row ids first (serial chase over small L2-hot next[])
        int rows[4];
        int cnt = 0;
        while (row >= 0 && cnt < 4) { rows[cnt++] = row; row = next[row]; }

        // batch-issue all payload loads (independent -> vmcnt pipelines)
        float4 dv[4];
        float  bet[4];
#pragma unroll
        for (int i = 0; i < 4; ++i) if (i < cnt) {
            dv[i]  = ((const float4*)(data + (size_t)rows[i] * kD))[lane];
            bet[i] = beta[rows[i]];
        }

#pragma unroll
        for (int i = 0; i < 4; ++i) if (i < cnt) {
            float nw[kM];
            float wsum = 0.f;
#pragma unroll
            for (int m = 0; m < kM; ++m) {
                const float dvb = bet[i] - csarr[m];
                const float wv = expf(-sqrtf(dvb * dvb + 1e-10f));
                nw[m] = wv;
                wsum += wv;
            }
            const float inv = 1.f / (wsum + kEPS + 1e-10f);
            float4 cm = make_float4(0.f, 0.f, 0.f, 0.f);
#pragma unroll
            for (int m = 0; m < kM; ++m) {
                const float w = nw[m] * inv;
                cm.x += w * cv[m].x; cm.y += w * cv[m].y;
                cm.z += w * cv[m].z; cm.w += w * cv[m].w;
                acc[m].x += w * dv[i].x; acc[m].y += w * dv[i].y;
                acc[m].z += w * dv[i].z; acc[m].w += w * dv[i].w;
                mwacc[m] += w;
            }
            const float ax = dv[i].x - cm.x, ay = dv[i].y - cm.y;
            const float az = dv[i].z - cm.z, aw = dv[i].w - cm.w;
            lossacc += ax * ax + ay * ay + az * az + aw * aw;
            if (lane < kM) sum_v[rows[i] * kM + lane] = csel;
        }
    }

    // mem_out = memory + acc (full coverage: every label, every chunk)
#pragma unroll
    for (int m = 0; m < kM; ++m) {
        float4 o;
        o.x = mv[m].x + acc[m].x; o.y = mv[m].y + acc[m].y;
        o.z = mv[m].z + acc[m].z; o.w = mv[m].w + acc[m].w;
        ((float4*)(mem_out + cbase + (size_t)m * kD))[lane] = o;
    }
    // mw_out (lane m writes element m; mwacc is lane-uniform)
    float msel = mwacc[0];
    msel = (lane == 1) ? mwacc[1] : msel;
    msel = (lane == 2) ? mwacc[2] : msel;
    msel = (lane == 3) ? mwacc[3] : msel;
    msel = (lane == 4) ? mwacc[4] : msel;
    msel = (lane == 5) ? mwacc[5] : msel;
    if (lane < kM) {
        const size_t i = (size_t)lab * kM + lane;
        mw_out[i] = memw[i] + msel;
    }

    // loss: wave shuffle -> LDS -> one atomic per block
#pragma unroll
    for (int off = 32; off > 0; off >>= 1) lossacc += __shfl_down(lossacc, off, 64);
    if (lane == 0) ls[wid] = lossacc;
    __syncthreads();
    if (threadIdx.x == 0) {
        const float s = ls[0] + ls[1] + ls[2] + ls[3];
        atomicAdd(loss_out, s * (1.f / ((float)kBS * (float)kD)));
    }
}

extern "C" void kernel_launch(void* const* d_in, const int* in_sizes, int n_in,
                              void* d_out, int out_size, void* d_ws, size_t ws_size,
                              hipStream_t stream) {
    const float* data    = (const float*)d_in[0];
    const int*   labels  = (const int*)  d_in[1];
    const float* beta    = (const float*)d_in[2];
    const float* centers = (const float*)d_in[3];
    const float* W1      = (const float*)d_in[4];
    const float* b1      = (const float*)d_in[5];
    const float* W2      = (const float*)d_in[6];
    const float* b2      = (const float*)d_in[7];
    const float* memory  = (const float*)d_in[8];
    const float* memw    = (const float*)d_in[9];

    float* out     = (float*)d_out;
    float* loss    = out;                                   // [1]
    float* sum_v   = out + 1;                               // [BS*M]
    float* mem_out = out + 1 + (size_t)kBS * kM;            // [C*M*D]
    float* mw_out  = mem_out + (size_t)kC * kM * kD;        // [C*M]

    // workspace layout
    int* head = (int*)d_ws;                                 // [C]
    int* next = head + kC;                                  // [BS]

    hipMemsetAsync(head, 0xFF, kC * sizeof(int), stream);   // head[i] = -1

    k_build<<<dim3((kBS + 255) / 256), dim3(256), 0, stream>>>(
        labels, head, next, loss);

    k_agg<<<dim3(kC / 4), dim3(256), 0, stream>>>(
        data, beta, head, next, W1, b1, W2, b2,
        centers, memory, memw, loss, sum_v, mem_out, mw_out);
}